// Round 2
// 589.527 us; speedup vs baseline: 1.2169x; 1.2169x over previous
//
#include <hip/hip_runtime.h>
#include <stdint.h>

constexpr int D_DIM   = 128;    // embedding dim
constexpr int C_CELLS = 1024;   // cells (32*32)
constexpr float EPS_D = 1.5e-3f; // suspect gap threshold (distance units)

typedef __attribute__((ext_vector_type(8))) short  short8;
typedef __attribute__((ext_vector_type(4))) float  floatx4;

#define GLOBAL_AS __attribute__((address_space(1)))
#define LDS_AS    __attribute__((address_space(3)))

__device__ __forceinline__ void gl2lds16(const void* g, void* l) {
    __builtin_amdgcn_global_load_lds((const GLOBAL_AS unsigned int*)g,
                                     (LDS_AS unsigned int*)l, 16, 0, 0);
}

__device__ __forceinline__ unsigned short f32_bf16_rtn(float x) {
    union { float f; unsigned u; } v; v.f = x;
    unsigned r = v.u + 0x7FFFu + ((v.u >> 16) & 1u);
    return (unsigned short)(r >> 16);
}
__device__ __forceinline__ float bf16_f32(unsigned short h) {
    union { float f; unsigned u; } v; v.u = ((unsigned)h) << 16; return v.f;
}
__device__ __forceinline__ float hi_f32(unsigned long long p) {
    union { float f; unsigned u; } v; v.u = (unsigned)(p >> 32); return v.f;
}

// ---------------- init: win=-1, flag=1, suspCount=0 ----------------
__global__ void init_kernel(int* win, int* flag, int* suspCount, int numNodes) {
    int j = blockIdx.x * blockDim.x + threadIdx.x;
    if (j < numNodes) win[j] = -1;
    if (j == 0) { *flag = 1; *suspCount = 0; }
}

// ------------- dtype probe: int64 nodes have all odd 32-bit words == 0 -------------
__global__ void detect_kernel(const int* nodes32, int n, int* flag) {
    int i = blockIdx.x * blockDim.x + threadIdx.x;
    if (i < n && (i & 1) && nodes32[i] != 0) *flag = 0;   // int32 data detected
}

// ------------- last-write-wins: winning batch index per node -------------
__global__ void winner_kernel(const void* nodes, int n, const int* flag, int* win) {
    int i = blockIdx.x * blockDim.x + threadIdx.x;
    if (i >= n) return;
    int node = (*flag) ? (int)((const long long*)nodes)[i]
                       : ((const int*)nodes)[i];
    atomicMax(&win[node], i);
}

// ------------- M squared norms (wave per row) -------------
__global__ void norms_kernel(const float* __restrict__ v, float* __restrict__ o, int rows) {
    int row  = blockIdx.x * 4 + (threadIdx.x >> 6);
    int lane = threadIdx.x & 63;
    if (row >= rows) return;
    float2 x = reinterpret_cast<const float2*>(v)[(size_t)row * 64 + lane];
    float s = x.x * x.x + x.y * x.y;
    #pragma unroll
    for (int m = 32; m; m >>= 1) s += __shfl_xor(s, m, 64);
    if (lane == 0) o[row] = s;
}

// ------------- precompute: M -> bf16 hi/lo, tile-swizzled for global_load_lds -------------
// dst layout: tile(64 cells) contiguous 16KB; within: r*128 + ((b ^ (r&15))<<3) shorts
__global__ void convB_kernel(const float* __restrict__ M,
                             unsigned short* __restrict__ Bh_g,
                             unsigned short* __restrict__ Bl_g) {
    int idx  = blockIdx.x * 256 + threadIdx.x;   // 0..16383 (cell, 16B-block)
    int cell = idx >> 4;
    int b    = idx & 15;
    const float4* s = reinterpret_cast<const float4*>(M + (size_t)cell * D_DIM + b * 8);
    float4 v0 = s[0], v1 = s[1];
    float xv[8] = { v0.x, v0.y, v0.z, v0.w, v1.x, v1.y, v1.z, v1.w };
    short8 hs, ls;
    #pragma unroll
    for (int j = 0; j < 8; ++j) {
        unsigned short hb = f32_bf16_rtn(xv[j]);
        unsigned short lb = f32_bf16_rtn(xv[j] - bf16_f32(hb));
        hs[j] = (short)hb; ls[j] = (short)lb;
    }
    int tile = cell >> 6, r = cell & 63;
    int dst = tile * 8192 + r * 128 + ((b ^ (r & 15)) << 3);
    *reinterpret_cast<short8*>(&Bh_g[dst]) = hs;
    *reinterpret_cast<short8*>(&Bl_g[dst]) = ls;
}

// ------------- main: D = M·X^T split-bf16 MFMA cdist + top-2 argmin + suspect list ----
// Per block: 64 X-rows x all 1024 cells (16 tiles of 64 cells).
// X fragments live in registers; single LDS buffer (reused A-stage) holds the
// current M tile; raw s_barrier + counted vmcnt keeps NT stores in flight.
__global__ __launch_bounds__(256, 3)
void dist_kernel(const float* __restrict__ X,
                 const unsigned short* __restrict__ Bh_g,
                 const unsigned short* __restrict__ Bl_g,
                 const float* __restrict__ msq,
                 float* __restrict__ outD, int* __restrict__ cells32,
                 int* __restrict__ suspects, int* __restrict__ suspCount,
                 int N)
{
    __shared__ __align__(16) unsigned short ldsH[64 * 128];  // A-stage hi, then B-tile hi
    __shared__ __align__(16) unsigned short ldsL[64 * 128];  // A-stage lo, then B-tile lo
    __shared__ float msq_s[C_CELLS];
    __shared__ float Axs[64];
    __shared__ unsigned long long sp1[64][2];
    __shared__ float              sm2[64][2];

    const int tid  = threadIdx.x;
    const int lane = tid & 63;
    const int wave = tid >> 6;
    const int q    = lane >> 4;    // quad id (0..3)
    const int l15  = lane & 15;
    const int w0   = wave & 1;     // cell half (0..1)
    const int w1   = wave >> 1;    // row half (0..1)
    const int blockRow = blockIdx.x * 64;
    const bool fullBlock = (blockRow + 64 <= N);

    // ---- stage A: 64 rows x 128 k, f32 -> bf16 hi/lo, swizzled; fused row-norms ----
    #pragma unroll
    for (int p = 0; p < 4; ++p) {
        int r = p * 16 + (tid >> 4);    // 0..63
        int b = tid & 15;               // 16-byte block index (8 bf16)
        int gRow = blockRow + r;
        float4 v0 = make_float4(0.f, 0.f, 0.f, 0.f), v1 = v0;
        if (gRow < N) {
            const float4* s = reinterpret_cast<const float4*>(X + (size_t)gRow * D_DIM + b * 8);
            v0 = s[0]; v1 = s[1];
        }
        float xv[8] = { v0.x, v0.y, v0.z, v0.w, v1.x, v1.y, v1.z, v1.w };
        short8 hs, ls;
        float sq = 0.f;
        #pragma unroll
        for (int j = 0; j < 8; ++j) {
            sq += xv[j] * xv[j];
            unsigned short hb = f32_bf16_rtn(xv[j]);
            unsigned short lb = f32_bf16_rtn(xv[j] - bf16_f32(hb));
            hs[j] = (short)hb; ls[j] = (short)lb;
        }
        #pragma unroll
        for (int m = 1; m < 16; m <<= 1) sq += __shfl_xor(sq, m, 16);
        if (b == 0) Axs[r] = sq;
        int ad = r * 128 + ((b ^ (r & 15)) << 3);
        *reinterpret_cast<short8*>(&ldsH[ad]) = hs;
        *reinterpret_cast<short8*>(&ldsL[ad]) = ls;
    }
    // stage msq -> LDS (1024 floats, 4 per thread)
    {
        float4 mv = *reinterpret_cast<const float4*>(&msq[tid * 4]);
        *reinterpret_cast<float4*>(&msq_s[tid * 4]) = mv;
    }
    __syncthreads();

    // ---- X fragments -> registers (reused across all 16 cell tiles) ----
    short8 xh[2][4], xl[2][4];
    #pragma unroll
    for (int t = 0; t < 2; ++t)
        #pragma unroll
        for (int kc = 0; kc < 4; ++kc) {
            int row = w1 * 32 + t * 16 + l15;          // row & 15 == l15
            int ad  = row * 128 + (((kc * 4 + q) ^ l15) << 3);
            xh[t][kc] = *reinterpret_cast<const short8*>(&ldsH[ad]);
            xl[t][kc] = *reinterpret_cast<const short8*>(&ldsL[ad]);
        }
    float xs[2];
    xs[0] = Axs[w1 * 32 + l15];
    xs[1] = Axs[w1 * 32 + 16 + l15];
    __syncthreads();   // all waves done reading A-stage; LDS now free for B tiles

    // ---- prologue: prefetch tile 0 into the reused LDS buffer ----
    {
        const char* bhg = (const char*)Bh_g + wave * 4096 + lane * 16;
        const char* blg = (const char*)Bl_g + wave * 4096 + lane * 16;
        char* bhl = (char*)ldsH + wave * 4096;
        char* bll = (char*)ldsL + wave * 4096;
        #pragma unroll
        for (int j = 0; j < 4; ++j) {
            gl2lds16(bhg + j * 1024, bhl + j * 1024);
            gl2lds16(blg + j * 1024, bll + j * 1024);
        }
    }
    asm volatile("s_waitcnt vmcnt(0)" ::: "memory");
    __builtin_amdgcn_sched_barrier(0);
    __builtin_amdgcn_s_barrier();
    __builtin_amdgcn_sched_barrier(0);

    float m1[2]  = { INFINITY, INFINITY };
    float m2v[2] = { INFINITY, INFINITY };
    int   c1[2]  = { 0, 0 };

    for (int ct = 0; ct < 16; ++ct) {
        floatx4 acc[2][2];
        #pragma unroll
        for (int t = 0; t < 2; ++t)
            #pragma unroll
            for (int u = 0; u < 2; ++u)
                acc[t][u] = (floatx4){0.f, 0.f, 0.f, 0.f};

        #pragma unroll
        for (int kc = 0; kc < 4; ++kc) {
            short8 mh[2], ml[2];
            #pragma unroll
            for (int u = 0; u < 2; ++u) {
                int cell = w0 * 32 + u * 16 + l15;     // cell & 15 == l15
                int ad   = cell * 128 + (((kc * 4 + q) ^ l15) << 3);
                mh[u] = *reinterpret_cast<const short8*>(&ldsH[ad]);
                ml[u] = *reinterpret_cast<const short8*>(&ldsL[ad]);
            }
            #pragma unroll
            for (int t = 0; t < 2; ++t)
                #pragma unroll
                for (int u = 0; u < 2; ++u) {
                    acc[t][u] = __builtin_amdgcn_mfma_f32_16x16x32_bf16(mh[u], xh[t][kc], acc[t][u], 0, 0, 0);
                    acc[t][u] = __builtin_amdgcn_mfma_f32_16x16x32_bf16(mh[u], xl[t][kc], acc[t][u], 0, 0, 0);
                    acc[t][u] = __builtin_amdgcn_mfma_f32_16x16x32_bf16(ml[u], xh[t][kc], acc[t][u], 0, 0, 0);
                }
        }

        // ---- epilogue into registers: d = sqrt(|x|^2 + |m|^2 - 2 dot); top-2 on d^2 ----
        // D = M·X^T fragment: lane holds x-row = l15, cells = q*4 + r (consecutive!)
        floatx4 dv[2][2];
        #pragma unroll
        for (int u = 0; u < 2; ++u) {
            int cbase = ct * 64 + w0 * 32 + u * 16 + q * 4;
            float4 ms4 = *reinterpret_cast<const float4*>(&msq_s[cbase]);
            float msv[4] = { ms4.x, ms4.y, ms4.z, ms4.w };
            #pragma unroll
            for (int t = 0; t < 2; ++t) {
                #pragma unroll
                for (int r = 0; r < 4; ++r) {
                    float s = fmaf(-2.0f, acc[t][u][r], xs[t] + msv[r]);
                    dv[t][u][r] = __builtin_amdgcn_sqrtf(fmaxf(s, 0.0f));
                    // top-2 (squared domain): med3 gives new 2nd-min in one instr
                    m2v[t] = __builtin_amdgcn_fmed3f(s, m1[t], m2v[t]);
                    c1[t]  = (s < m1[t]) ? (cbase + r) : c1[t];
                    m1[t]  = fminf(s, m1[t]);
                }
            }
        }

        __builtin_amdgcn_s_barrier();          // B1: all waves done reading tile ct
        __builtin_amdgcn_sched_barrier(0);
        if (ct < 15) {                          // prefetch tile ct+1 over it
            const char* bhg = (const char*)Bh_g + (size_t)(ct + 1) * 16384 + wave * 4096 + lane * 16;
            const char* blg = (const char*)Bl_g + (size_t)(ct + 1) * 16384 + wave * 4096 + lane * 16;
            char* bhl = (char*)ldsH + wave * 4096;
            char* bll = (char*)ldsL + wave * 4096;
            #pragma unroll
            for (int j = 0; j < 4; ++j) {
                gl2lds16(bhg + j * 1024, bhl + j * 1024);
                gl2lds16(blg + j * 1024, bll + j * 1024);
            }
        }
        // coalesced float4 NT stores, issued AFTER the gl2lds so counted vmcnt works
        #pragma unroll
        for (int t = 0; t < 2; ++t) {
            int grow = blockRow + w1 * 32 + t * 16 + l15;
            if (grow < N) {
                size_t rb = (size_t)grow * C_CELLS + ct * 64 + w0 * 32 + q * 4;
                __builtin_nontemporal_store(dv[t][0], reinterpret_cast<floatx4*>(&outD[rb]));
                __builtin_nontemporal_store(dv[t][1], reinterpret_cast<floatx4*>(&outD[rb + 16]));
            }
        }
        __builtin_amdgcn_sched_barrier(0);
        if (ct < 15) {
            // 8 gl2lds are older than the 4 stores: vmcnt(4) drains the loads only.
            // Tail block may mask off stores -> count unsafe -> full drain (uniform).
            if (fullBlock) asm volatile("s_waitcnt vmcnt(4)" ::: "memory");
            else           asm volatile("s_waitcnt vmcnt(0)" ::: "memory");
            __builtin_amdgcn_sched_barrier(0);
            __builtin_amdgcn_s_barrier();      // B2: tile ct+1 visible to all waves
            __builtin_amdgcn_sched_barrier(0);
        }
    }

    // ---- top-2 reduce across the 4 q-lanes sharing each row ----
    #pragma unroll
    for (int t = 0; t < 2; ++t) {
        float a1 = m1[t], a2 = m2v[t]; int ac = c1[t];
        #pragma unroll
        for (int off = 16; off <= 32; off <<= 1) {
            float b1 = __shfl_xor(a1, off, 64);
            float b2 = __shfl_xor(a2, off, 64);
            int   bc = __shfl_xor(ac, off, 64);
            float hi = fmaxf(a1, b1);
            ac = (b1 < a1) ? bc : ac;
            a1 = fminf(a1, b1);
            a2 = fminf(fminf(a2, b2), hi);
        }
        if (q == 0) {
            int lr = w1 * 32 + t * 16 + l15;
            float d1 = __builtin_amdgcn_sqrtf(fmaxf(a1, 0.0f));
            float d2 = __builtin_amdgcn_sqrtf(fmaxf(a2, 0.0f));
            union { float f; unsigned u; } bu; bu.f = d1;
            sp1[lr][w0] = ((unsigned long long)bu.u << 32) | (unsigned)ac;
            sm2[lr][w0] = d2;
        }
    }
    __syncthreads();
    // ---- cross-wave merge: one thread per row; write cell + suspect test ----
    if (tid < 64) {
        int g = blockRow + tid;
        if (g < N) {
            unsigned long long a = sp1[tid][0], b = sp1[tid][1];
            unsigned long long G1 = (a < b) ? a : b;
            unsigned long long hi = (a < b) ? b : a;
            float M2  = fminf(fminf(sm2[tid][0], sm2[tid][1]), hi_f32(hi));
            float g1v = hi_f32(G1);
            cells32[g] = (int)(G1 & 0xffffffffu);
            if (M2 - g1v < EPS_D) {
                int ix = atomicAdd(suspCount, 1);
                suspects[ix] = g;
            }
        }
    }
}

// ------------- refine: exact f64 argmin for near-tie rows -------------
__global__ __launch_bounds__(256)
void refine_kernel(const float* __restrict__ X, const float* __restrict__ M,
                   const int* __restrict__ suspects, const int* __restrict__ suspCount,
                   int* __restrict__ cells32)
{
    __shared__ double xd[128];
    __shared__ unsigned long long wres[4];
    int cnt = *suspCount;
    for (int s = blockIdx.x; s < cnt; s += gridDim.x) {
        int row = suspects[s];
        if (threadIdx.x < 128) xd[threadIdx.x] = (double)X[(size_t)row * D_DIM + threadIdx.x];
        __syncthreads();
        unsigned long long best = ~0ull;
        for (int c = threadIdx.x; c < C_CELLS; c += 256) {
            const float* mp = M + (size_t)c * D_DIM;
            double acc = 0.0;
            #pragma unroll 4
            for (int k = 0; k < D_DIM; ++k) {
                double diff = xd[k] - (double)mp[k];
                acc = fma(diff, diff, acc);
            }
            unsigned long long bits = (unsigned long long)__double_as_longlong(acc);
            unsigned long long pk = (bits & ~1023ull) | (unsigned long long)c;
            if (pk < best) best = pk;
        }
        #pragma unroll
        for (int m = 32; m; m >>= 1) {
            unsigned long long o = __shfl_xor(best, m, 64);
            if (o < best) best = o;
        }
        if ((threadIdx.x & 63) == 0) wres[threadIdx.x >> 6] = best;
        __syncthreads();
        if (threadIdx.x == 0) {
            unsigned long long b0 = wres[0] < wres[1] ? wres[0] : wres[1];
            unsigned long long b1 = wres[2] < wres[3] ? wres[2] : wres[3];
            unsigned long long b  = b0 < b1 ? b0 : b1;
            cells32[row] = (int)(b & 1023ull);
        }
        __syncthreads();
    }
}

// ------------- finalize: cells + scatter outputs (all written as f32 values) -------------
__global__ void post_kernel(const int* __restrict__ cells32,
                            const int* __restrict__ win,
                            const float* __restrict__ times,
                            const int* __restrict__ node_cell,
                            const float* __restrict__ node_time,
                            float* __restrict__ outCells,
                            float* __restrict__ outNC,
                            float* __restrict__ outNT,
                            int n, int numNodes)
{
    int j = blockIdx.x * blockDim.x + threadIdx.x;
    if (j < n) outCells[j] = (float)cells32[j];
    if (j < numNodes) {
        int w = win[j];
        float c, t;
        if (w >= 0) {
            c = (float)cells32[w];
            t = times[w];
        } else {
            c = (float)node_cell[j];
            t = node_time[j];
        }
        outNC[j] = c;
        outNT[j] = t;
    }
}

extern "C" void kernel_launch(void* const* d_in, const int* in_sizes, int n_in,
                              void* d_out, int out_size, void* d_ws, size_t ws_size,
                              hipStream_t stream)
{
    const float* X         = (const float*)d_in[0];   // [N, 128]
    const float* M         = (const float*)d_in[1];   // [1024, 128]
    const void*  nodes     = d_in[2];                 // [N] int32 or int64
    const float* times     = (const float*)d_in[3];   // [N]
    const int*   node_cell = (const int*)d_in[4];     // [numNodes]
    const float* node_time = (const float*)d_in[5];   // [numNodes]

    const int N        = in_sizes[3];
    const int numNodes = in_sizes[4];
    const int C        = in_sizes[1] / D_DIM;         // 1024

    // workspace layout (~5.7 MB)
    char* ws = (char*)d_ws;
    size_t off = 0;
    unsigned short* Bh_g = (unsigned short*)(ws + off); off += (size_t)C * D_DIM * 2;
    unsigned short* Bl_g = (unsigned short*)(ws + off); off += (size_t)C * D_DIM * 2;
    int* win      = (int*)(ws + off); off += (size_t)numNodes * 4;
    int* cells32  = (int*)(ws + off); off += (size_t)N * 4;
    int* suspects = (int*)(ws + off); off += (size_t)N * 4;
    float* msq    = (float*)(ws + off); off += (size_t)C * 4;
    int* flag     = (int*)(ws + off); off += 4;
    int* suspCount= (int*)(ws + off); off += 4;
    (void)ws_size; (void)n_in; (void)out_size;

    float* outD     = (float*)d_out;                  // [N,1024] distances
    float* outCells = outD + (size_t)N * C;           // [N] cells (as f32)
    float* outNC    = outCells + N;                   // [numNodes] node_cell (as f32)
    float* outNT    = outNC + numNodes;               // [numNodes] node_time

    init_kernel  <<<(numNodes + 255) / 256, 256, 0, stream>>>(win, flag, suspCount, numNodes);
    detect_kernel<<<(N + 255) / 256, 256, 0, stream>>>((const int*)nodes, N, flag);
    winner_kernel<<<(N + 255) / 256, 256, 0, stream>>>(nodes, N, flag, win);
    norms_kernel <<<(C + 3) / 4, 256, 0, stream>>>(M, msq, C);
    convB_kernel <<<(C * 16 + 255) / 256, 256, 0, stream>>>(M, Bh_g, Bl_g);
    dist_kernel  <<<(N + 63) / 64, 256, 0, stream>>>(X, Bh_g, Bl_g, msq, outD, cells32,
                                                     suspects, suspCount, N);
    refine_kernel<<<512, 256, 0, stream>>>(X, M, suspects, suspCount, cells32);
    post_kernel  <<<(numNodes + 255) / 256, 256, 0, stream>>>(cells32, win, times, node_cell,
                                                              node_time, outCells, outNC, outNT,
                                                              N, numNodes);
}

// Round 4
// 577.373 us; speedup vs baseline: 1.2425x; 1.0211x over previous
//
#include <hip/hip_runtime.h>
#include <stdint.h>

constexpr int D_DIM   = 128;    // embedding dim
constexpr int C_CELLS = 1024;   // cells (32*32)
constexpr float EPS_D = 1.5e-3f; // suspect gap threshold (distance units)

typedef __attribute__((ext_vector_type(8))) short  short8;
typedef __attribute__((ext_vector_type(4))) float  floatx4;

#define GLOBAL_AS __attribute__((address_space(1)))
#define LDS_AS    __attribute__((address_space(3)))

__device__ __forceinline__ void gl2lds16(const void* g, void* l) {
    __builtin_amdgcn_global_load_lds((const GLOBAL_AS unsigned int*)g,
                                     (LDS_AS unsigned int*)l, 16, 0, 0);
}

__device__ __forceinline__ unsigned short f32_bf16_rtn(float x) {
    union { float f; unsigned u; } v; v.f = x;
    unsigned r = v.u + 0x7FFFu + ((v.u >> 16) & 1u);
    return (unsigned short)(r >> 16);
}
__device__ __forceinline__ float bf16_f32(unsigned short h) {
    union { float f; unsigned u; } v; v.u = ((unsigned)h) << 16; return v.f;
}
__device__ __forceinline__ float hi_f32(unsigned long long p) {
    union { float f; unsigned u; } v; v.u = (unsigned)(p >> 32); return v.f;
}

// ---------------- init: win=-1, flag=1, suspCount=0 ----------------
__global__ void init_kernel(int* win, int* flag, int* suspCount, int numNodes) {
    int j = blockIdx.x * blockDim.x + threadIdx.x;
    if (j < numNodes) win[j] = -1;
    if (j == 0) { *flag = 1; *suspCount = 0; }
}

// ------------- dtype probe: int64 nodes have all odd 32-bit words == 0 -------------
__global__ void detect_kernel(const int* nodes32, int n, int* flag) {
    int i = blockIdx.x * blockDim.x + threadIdx.x;
    if (i < n && (i & 1) && nodes32[i] != 0) *flag = 0;   // int32 data detected
}

// ------------- last-write-wins: winning batch index per node -------------
__global__ void winner_kernel(const void* nodes, int n, const int* flag, int* win) {
    int i = blockIdx.x * blockDim.x + threadIdx.x;
    if (i >= n) return;
    int node = (*flag) ? (int)((const long long*)nodes)[i]
                       : ((const int*)nodes)[i];
    atomicMax(&win[node], i);
}

// ------------- precompute: M -> bf16 hi/lo tile-swizzled + fused M row norms -------------
// dst layout: tile(64 cells) contiguous 16KB; within: r*128 + ((b ^ (r&15))<<3) shorts
__global__ void convB_kernel(const float* __restrict__ M,
                             unsigned short* __restrict__ Bh_g,
                             unsigned short* __restrict__ Bl_g,
                             float* __restrict__ msq) {
    int idx  = blockIdx.x * 256 + threadIdx.x;   // 0..16383 (cell, 16B-block)
    int cell = idx >> 4;
    int b    = idx & 15;
    const float4* s = reinterpret_cast<const float4*>(M + (size_t)cell * D_DIM + b * 8);
    float4 v0 = s[0], v1 = s[1];
    float xv[8] = { v0.x, v0.y, v0.z, v0.w, v1.x, v1.y, v1.z, v1.w };
    short8 hs, ls;
    float sq = 0.f;
    #pragma unroll
    for (int j = 0; j < 8; ++j) {
        sq += xv[j] * xv[j];
        unsigned short hb = f32_bf16_rtn(xv[j]);
        unsigned short lb = f32_bf16_rtn(xv[j] - bf16_f32(hb));
        hs[j] = (short)hb; ls[j] = (short)lb;
    }
    // norm reduce across the 16 lanes sharing this cell (16 consecutive lanes)
    #pragma unroll
    for (int m = 1; m < 16; m <<= 1) sq += __shfl_xor(sq, m, 16);
    if (b == 0) msq[cell] = sq;
    int tile = cell >> 6, r = cell & 63;
    int dst = tile * 8192 + r * 128 + ((b ^ (r & 15)) << 3);
    *reinterpret_cast<short8*>(&Bh_g[dst]) = hs;
    *reinterpret_cast<short8*>(&Bl_g[dst]) = ls;
}

// ------------- main: D = M·X^T split-bf16 MFMA cdist + top-2 argmin + suspect list ----
// Per block: 64 X-rows x all 1024 cells (16 tiles of 64 cells).
// X fragments in registers; single LDS B-tile buffer; per-tile output staged in a
// swizzled 16KB LDS buffer then stored as 128B-aligned full lines (8 lanes x 16B/row).
// Raw s_barrier + counted vmcnt keeps NT stores in flight across barriers.
__global__ __launch_bounds__(256, 3)
void dist_kernel(const float* __restrict__ X,
                 const unsigned short* __restrict__ Bh_g,
                 const unsigned short* __restrict__ Bl_g,
                 const float* __restrict__ msq,
                 float* __restrict__ outD, int* __restrict__ cells32,
                 int* __restrict__ suspects, int* __restrict__ suspCount,
                 int N)
{
    // 52KB carve: 3 blocks/CU. Overlays are barrier-separated (see comments).
    __shared__ __align__(16) char smem[53248];
    unsigned short* ldsH  = reinterpret_cast<unsigned short*>(smem);           // 16KB B-tile hi (A-stage hi first)
    unsigned short* ldsL  = reinterpret_cast<unsigned short*>(smem + 16384);   // 16KB B-tile lo (A-stage lo first)
    float*          stage = reinterpret_cast<float*>(smem + 32768);            // 16KB output tile staging
    float*          msq_s = reinterpret_cast<float*>(smem + 49152);            // 4KB
    float*          Axs   = reinterpret_cast<float*>(smem + 32768);            // overlay: read before stage's 1st write
    unsigned long long* sp1 = reinterpret_cast<unsigned long long*>(smem + 49152); // overlay msq_s: written after last msq read
    float*          sm2   = reinterpret_cast<float*>(smem + 49152 + 1024);

    const int tid  = threadIdx.x;
    const int lane = tid & 63;
    const int wave = tid >> 6;
    const int q    = lane >> 4;    // quad id (0..3)
    const int l15  = lane & 15;
    const int w0   = wave & 1;     // cell half (0..1)
    const int w1   = wave >> 1;    // row half (0..1)
    const int blockRow = blockIdx.x * 64;
    const bool fullBlock = (blockRow + 64 <= N);

    // ---- stage A: 64 rows x 128 k, f32 -> bf16 hi/lo, swizzled; fused row-norms ----
    #pragma unroll
    for (int p = 0; p < 4; ++p) {
        int r = p * 16 + (tid >> 4);    // 0..63
        int b = tid & 15;               // 16-byte block index (8 bf16)
        int gRow = blockRow + r;
        float4 v0 = make_float4(0.f, 0.f, 0.f, 0.f), v1 = v0;
        if (gRow < N) {
            const float4* s = reinterpret_cast<const float4*>(X + (size_t)gRow * D_DIM + b * 8);
            v0 = s[0]; v1 = s[1];
        }
        float xv[8] = { v0.x, v0.y, v0.z, v0.w, v1.x, v1.y, v1.z, v1.w };
        short8 hs, ls;
        float sq = 0.f;
        #pragma unroll
        for (int j = 0; j < 8; ++j) {
            sq += xv[j] * xv[j];
            unsigned short hb = f32_bf16_rtn(xv[j]);
            unsigned short lb = f32_bf16_rtn(xv[j] - bf16_f32(hb));
            hs[j] = (short)hb; ls[j] = (short)lb;
        }
        #pragma unroll
        for (int m = 1; m < 16; m <<= 1) sq += __shfl_xor(sq, m, 16);
        if (b == 0) Axs[r] = sq;
        int ad = r * 128 + ((b ^ (r & 15)) << 3);
        *reinterpret_cast<short8*>(&ldsH[ad]) = hs;
        *reinterpret_cast<short8*>(&ldsL[ad]) = ls;
    }
    // stage msq -> LDS (1024 floats, 4 per thread)
    {
        float4 mv = *reinterpret_cast<const float4*>(&msq[tid * 4]);
        *reinterpret_cast<float4*>(&msq_s[tid * 4]) = mv;
    }
    __syncthreads();

    // ---- X fragments -> registers (reused across all 16 cell tiles) ----
    short8 xh[2][4], xl[2][4];
    #pragma unroll
    for (int t = 0; t < 2; ++t)
        #pragma unroll
        for (int kc = 0; kc < 4; ++kc) {
            int row = w1 * 32 + t * 16 + l15;          // row & 15 == l15
            int ad  = row * 128 + (((kc * 4 + q) ^ l15) << 3);
            xh[t][kc] = *reinterpret_cast<const short8*>(&ldsH[ad]);
            xl[t][kc] = *reinterpret_cast<const short8*>(&ldsL[ad]);
        }
    float xs[2];
    xs[0] = Axs[w1 * 32 + l15];
    xs[1] = Axs[w1 * 32 + 16 + l15];
    __syncthreads();   // all waves done reading A-stage/Axs; LDS free for B tiles + stage

    // ---- prologue: prefetch tile 0 into the reused LDS buffer ----
    {
        const char* bhg = (const char*)Bh_g + wave * 4096 + lane * 16;
        const char* blg = (const char*)Bl_g + wave * 4096 + lane * 16;
        char* bhl = (char*)ldsH + wave * 4096;
        char* bll = (char*)ldsL + wave * 4096;
        #pragma unroll
        for (int j = 0; j < 4; ++j) {
            gl2lds16(bhg + j * 1024, bhl + j * 1024);
            gl2lds16(blg + j * 1024, bll + j * 1024);
        }
    }
    asm volatile("s_waitcnt vmcnt(0)" ::: "memory");
    __builtin_amdgcn_sched_barrier(0);
    __builtin_amdgcn_s_barrier();
    __builtin_amdgcn_sched_barrier(0);

    float m1[2]  = { INFINITY, INFINITY };
    float m2v[2] = { INFINITY, INFINITY };
    int   c1[2]  = { 0, 0 };

    for (int ct = 0; ct < 16; ++ct) {
        floatx4 acc[2][2];
        #pragma unroll
        for (int t = 0; t < 2; ++t)
            #pragma unroll
            for (int u = 0; u < 2; ++u)
                acc[t][u] = (floatx4){0.f, 0.f, 0.f, 0.f};

        #pragma unroll
        for (int kc = 0; kc < 4; ++kc) {
            short8 mh[2], ml[2];
            #pragma unroll
            for (int u = 0; u < 2; ++u) {
                int cell = w0 * 32 + u * 16 + l15;     // cell & 15 == l15
                int ad   = cell * 128 + (((kc * 4 + q) ^ l15) << 3);
                mh[u] = *reinterpret_cast<const short8*>(&ldsH[ad]);
                ml[u] = *reinterpret_cast<const short8*>(&ldsL[ad]);
            }
            #pragma unroll
            for (int t = 0; t < 2; ++t)
                #pragma unroll
                for (int u = 0; u < 2; ++u) {
                    acc[t][u] = __builtin_amdgcn_mfma_f32_16x16x32_bf16(mh[u], xh[t][kc], acc[t][u], 0, 0, 0);
                    acc[t][u] = __builtin_amdgcn_mfma_f32_16x16x32_bf16(mh[u], xl[t][kc], acc[t][u], 0, 0, 0);
                    acc[t][u] = __builtin_amdgcn_mfma_f32_16x16x32_bf16(ml[u], xh[t][kc], acc[t][u], 0, 0, 0);
                }
        }

        // ---- epilogue: d = sqrt(|x|^2+|m|^2-2dot); top-2 on d^2; tile -> swizzled stage ----
        // D = M·X^T fragment: lane holds x-row = l15, cells = q*4 + r (consecutive)
        #pragma unroll
        for (int u = 0; u < 2; ++u) {
            int cbase = ct * 64 + w0 * 32 + u * 16 + q * 4;
            float4 ms4 = *reinterpret_cast<const float4*>(&msq_s[cbase]);
            float msv[4] = { ms4.x, ms4.y, ms4.z, ms4.w };
            #pragma unroll
            for (int t = 0; t < 2; ++t) {
                floatx4 dvv;
                #pragma unroll
                for (int r = 0; r < 4; ++r) {
                    float s = fmaf(-2.0f, acc[t][u][r], xs[t] + msv[r]);
                    dvv[r] = __builtin_amdgcn_sqrtf(fmaxf(s, 0.0f));
                    // top-2 (squared domain): med3 gives new 2nd-min in one instr
                    m2v[t] = __builtin_amdgcn_fmed3f(s, m1[t], m2v[t]);
                    c1[t]  = (s < m1[t]) ? (cbase + r) : c1[t];
                    m1[t]  = fminf(s, m1[t]);
                }
                // stage[row][16B-unit u4 ^ (row&15)] — conflict-free (A-stage pattern)
                int row  = w1 * 32 + t * 16 + l15;
                int u4   = w0 * 8 + u * 4 + q;
                int unit = row * 16 + (u4 ^ l15);
                *reinterpret_cast<floatx4*>(&stage[unit * 4]) = dvv;
            }
        }

        asm volatile("s_waitcnt lgkmcnt(0)" ::: "memory");  // stage writes visible
        __builtin_amdgcn_sched_barrier(0);
        __builtin_amdgcn_s_barrier();          // B1: tile ct LDS reads + stage writes done
        __builtin_amdgcn_sched_barrier(0);
        if (ct < 15) {                          // prefetch tile ct+1 over B buffers
            const char* bhg = (const char*)Bh_g + (size_t)(ct + 1) * 16384 + wave * 4096 + lane * 16;
            const char* blg = (const char*)Bl_g + (size_t)(ct + 1) * 16384 + wave * 4096 + lane * 16;
            char* bhl = (char*)ldsH + wave * 4096;
            char* bll = (char*)ldsL + wave * 4096;
            #pragma unroll
            for (int j = 0; j < 4; ++j) {
                gl2lds16(bhg + j * 1024, bhl + j * 1024);
                gl2lds16(blg + j * 1024, bll + j * 1024);
            }
        }
        // full-line NT stores from stage: per instruction 8 rows x 128B aligned runs
        #pragma unroll
        for (int j = 0; j < 4; ++j) {
            int row = (wave << 4) + ((j >> 1) << 3) + (lane >> 3);
            int u4r = (lane & 7) + ((j & 1) << 3);
            floatx4 v = *reinterpret_cast<const floatx4*>(&stage[(row * 16 + (u4r ^ (row & 15))) * 4]);
            int grow = blockRow + row;
            if (grow < N) {
                __builtin_nontemporal_store(v,
                    reinterpret_cast<floatx4*>(&outD[(size_t)grow * C_CELLS + ct * 64 + u4r * 4]));
            }
        }
        __builtin_amdgcn_sched_barrier(0);
        if (ct < 15) {
            // 8 gl2lds are older than the 4 stores: vmcnt(4) drains the loads only.
            // Tail block may mask off stores -> count unsafe -> full drain (uniform).
            if (fullBlock) asm volatile("s_waitcnt vmcnt(4)" ::: "memory");
            else           asm volatile("s_waitcnt vmcnt(0)" ::: "memory");
            __builtin_amdgcn_sched_barrier(0);
            __builtin_amdgcn_s_barrier();      // B2: tile ct+1 visible to all waves
            __builtin_amdgcn_sched_barrier(0);
        }
    }

    // ---- top-2 reduce across the 16 lanes sharing each row ----
    #pragma unroll
    for (int t = 0; t < 2; ++t) {
        float a1 = m1[t], a2 = m2v[t]; int ac = c1[t];
        #pragma unroll
        for (int off = 16; off <= 32; off <<= 1) {
            float b1 = __shfl_xor(a1, off, 64);
            float b2 = __shfl_xor(a2, off, 64);
            int   bc = __shfl_xor(ac, off, 64);
            float hi = fmaxf(a1, b1);
            ac = (b1 < a1) ? bc : ac;
            a1 = fminf(a1, b1);
            a2 = fminf(fminf(a2, b2), hi);
        }
        if (q == 0) {
            int lr = w1 * 32 + t * 16 + l15;
            float d1 = __builtin_amdgcn_sqrtf(fmaxf(a1, 0.0f));
            float d2 = __builtin_amdgcn_sqrtf(fmaxf(a2, 0.0f));
            union { float f; unsigned u; } bu; bu.f = d1;
            sp1[lr * 2 + w0] = ((unsigned long long)bu.u << 32) | (unsigned)ac;
            sm2[lr * 2 + w0] = d2;
        }
    }
    __syncthreads();
    // ---- cross-wave merge: one thread per row; write cell + suspect test ----
    if (tid < 64) {
        int g = blockRow + tid;
        if (g < N) {
            unsigned long long a = sp1[tid * 2 + 0], b = sp1[tid * 2 + 1];
            unsigned long long G1 = (a < b) ? a : b;
            unsigned long long hi = (a < b) ? b : a;
            float M2  = fminf(fminf(sm2[tid * 2 + 0], sm2[tid * 2 + 1]), hi_f32(hi));
            float g1v = hi_f32(G1);
            cells32[g] = (int)(G1 & 0xffffffffu);
            if (M2 - g1v < EPS_D) {
                int ix = atomicAdd(suspCount, 1);
                suspects[ix] = g;
            }
        }
    }
}

// ------------- refine: exact f64 argmin for near-tie rows -------------
__global__ __launch_bounds__(256)
void refine_kernel(const float* __restrict__ X, const float* __restrict__ M,
                   const int* __restrict__ suspects, const int* __restrict__ suspCount,
                   int* __restrict__ cells32)
{
    __shared__ double xd[128];
    __shared__ unsigned long long wres[4];
    int cnt = *suspCount;
    for (int s = blockIdx.x; s < cnt; s += gridDim.x) {
        int row = suspects[s];
        if (threadIdx.x < 128) xd[threadIdx.x] = (double)X[(size_t)row * D_DIM + threadIdx.x];
        __syncthreads();
        unsigned long long best = ~0ull;
        for (int c = threadIdx.x; c < C_CELLS; c += 256) {
            const float* mp = M + (size_t)c * D_DIM;
            double acc = 0.0;
            #pragma unroll 4
            for (int k = 0; k < D_DIM; ++k) {
                double diff = xd[k] - (double)mp[k];
                acc = fma(diff, diff, acc);
            }
            unsigned long long bits = (unsigned long long)__double_as_longlong(acc);
            unsigned long long pk = (bits & ~1023ull) | (unsigned long long)c;
            if (pk < best) best = pk;
        }
        #pragma unroll
        for (int m = 32; m; m >>= 1) {
            unsigned long long o = __shfl_xor(best, m, 64);
            if (o < best) best = o;
        }
        if ((threadIdx.x & 63) == 0) wres[threadIdx.x >> 6] = best;
        __syncthreads();
        if (threadIdx.x == 0) {
            unsigned long long b0 = wres[0] < wres[1] ? wres[0] : wres[1];
            unsigned long long b1 = wres[2] < wres[3] ? wres[2] : wres[3];
            unsigned long long b  = b0 < b1 ? b0 : b1;
            cells32[row] = (int)(b & 1023ull);
        }
        __syncthreads();
    }
}

// ------------- finalize: cells + scatter outputs (all written as f32 values) -------------
__global__ void post_kernel(const int* __restrict__ cells32,
                            const int* __restrict__ win,
                            const float* __restrict__ times,
                            const int* __restrict__ node_cell,
                            const float* __restrict__ node_time,
                            float* __restrict__ outCells,
                            float* __restrict__ outNC,
                            float* __restrict__ outNT,
                            int n, int numNodes)
{
    int j = blockIdx.x * blockDim.x + threadIdx.x;
    if (j < n) outCells[j] = (float)cells32[j];
    if (j < numNodes) {
        int w = win[j];
        float c, t;
        if (w >= 0) {
            c = (float)cells32[w];
            t = times[w];
        } else {
            c = (float)node_cell[j];
            t = node_time[j];
        }
        outNC[j] = c;
        outNT[j] = t;
    }
}

extern "C" void kernel_launch(void* const* d_in, const int* in_sizes, int n_in,
                              void* d_out, int out_size, void* d_ws, size_t ws_size,
                              hipStream_t stream)
{
    const float* X         = (const float*)d_in[0];   // [N, 128]
    const float* M         = (const float*)d_in[1];   // [1024, 128]
    const void*  nodes     = d_in[2];                 // [N] int32 or int64
    const float* times     = (const float*)d_in[3];   // [N]
    const int*   node_cell = (const int*)d_in[4];     // [numNodes]
    const float* node_time = (const float*)d_in[5];   // [numNodes]

    const int N        = in_sizes[3];
    const int numNodes = in_sizes[4];
    const int C        = in_sizes[1] / D_DIM;         // 1024

    // workspace layout (~5.7 MB)
    char* ws = (char*)d_ws;
    size_t off = 0;
    unsigned short* Bh_g = (unsigned short*)(ws + off); off += (size_t)C * D_DIM * 2;
    unsigned short* Bl_g = (unsigned short*)(ws + off); off += (size_t)C * D_DIM * 2;
    int* win      = (int*)(ws + off); off += (size_t)numNodes * 4;
    int* cells32  = (int*)(ws + off); off += (size_t)N * 4;
    int* suspects = (int*)(ws + off); off += (size_t)N * 4;
    float* msq    = (float*)(ws + off); off += (size_t)C * 4;
    int* flag     = (int*)(ws + off); off += 4;
    int* suspCount= (int*)(ws + off); off += 4;
    (void)ws_size; (void)n_in; (void)out_size;

    float* outD     = (float*)d_out;                  // [N,1024] distances
    float* outCells = outD + (size_t)N * C;           // [N] cells (as f32)
    float* outNC    = outCells + N;                   // [numNodes] node_cell (as f32)
    float* outNT    = outNC + numNodes;               // [numNodes] node_time

    init_kernel  <<<(numNodes + 255) / 256, 256, 0, stream>>>(win, flag, suspCount, numNodes);
    detect_kernel<<<(N + 255) / 256, 256, 0, stream>>>((const int*)nodes, N, flag);
    winner_kernel<<<(N + 255) / 256, 256, 0, stream>>>(nodes, N, flag, win);
    convB_kernel <<<(C * 16 + 255) / 256, 256, 0, stream>>>(M, Bh_g, Bl_g, msq);
    dist_kernel  <<<(N + 63) / 64, 256, 0, stream>>>(X, Bh_g, Bl_g, msq, outD, cells32,
                                                     suspects, suspCount, N);
    refine_kernel<<<512, 256, 0, stream>>>(X, M, suspects, suspCount, cells32);
    post_kernel  <<<(numNodes + 255) / 256, 256, 0, stream>>>(cells32, win, times, node_cell,
                                                              node_time, outCells, outNC, outNT,
                                                              N, numNodes);
}